// Round 4
// baseline (341.578 us; speedup 1.0000x reference)
//
#include <hip/hip_runtime.h>

// YOLO-v1 loss, fp32, N=16384, S=7, B=2, C=20 → 30 floats/cell, 802816 cells.
// R12. Post-mortem of R9/R11: kernel = 72us, effective read 2.68 TB/s — the
// exact "~2.7 TB/s pin" of R1-R6. But R8 (NT loads) was absent from round-0's
// top-5 (all fills >=56.0us) while this round's capture proves yolo dispatches
// ARE profiled => R8's kernel was <56.5us => NT loads BEAT the pin. R9 dropped
// NT and went per-lane strided target (2 bundled changes) → regression.
// Theory: pin = L2 miss/allocate path (~1.1 line-fills/cyc/XCD, structure-
// independent); `nt` no-allocate loads bypass it for this read-once stream.
// VALUBusy 7%, conflicts 0, in-flight bytes ~10x concurrency requirement →
// nothing else is the bound.
// R12 = (1) NT dense dwordx4 for BOTH inputs (no strided loads),
//       (2) single latency window: both NT bursts → VGPRs, then sequential
//           LDS round trips in the shared wave region (clobber orders LDS
//           reuse only; target loads already issued above it),
//       (3) fused final reduce: last block (device-scope atomic ticket +
//           threadfence) re-runs the old reduce loop BIT-EXACTLY → absmax 0.0.
//           4-byte hipMemsetAsync zeroes the ticket each graph replay.
// Predict: kernel <=56us (maybe 45-50), FETCH ~94MB, reduce dispatch gone,
// dur_us 206 → 175-190. If kernel pins at ~71 despite NT → NT theory wrong.

typedef float vfloat4 __attribute__((ext_vector_type(4)));

constexpr int S = 7;
constexpr int FPC = 30;           // floats per cell
constexpr int BLK = 256;          // 4 waves
constexpr int WAVES = BLK / 64;
constexpr int TILE_F4 = 64 * FPC / 4;   // 480 float4 per wave tile
constexpr float STEP = 1.0f / 7.0f;
constexpr float EPS = 1e-10f;

__global__ __launch_bounds__(BLK) void yolo_fused_kernel(
    const float* __restrict__ pred,
    const float* __restrict__ target,
    float* __restrict__ partial,
    unsigned int* __restrict__ ticket_ctr,
    float* __restrict__ out,
    int nblocks, float invN) {
  __shared__ float lds[WAVES][64 * FPC];   // 7680 B per wave region
  __shared__ float wsum[WAVES];
  __shared__ unsigned int ticket;

  const int tid = threadIdx.x;
  const int lane = tid & 63;
  const int wid = tid >> 6;
  const int cellw = blockIdx.x * BLK + wid * 64;  // wave's first cell
  const int cell = cellw + lane;

  float* myld = lds[wid];

  // ---- single latency window: both inputs, dense wave-contiguous NT 16B ----
  vfloat4 pr[8], tr[8];
  {
    const vfloat4* gp = (const vfloat4*)(pred + (size_t)cellw * FPC);
    const vfloat4* gt = (const vfloat4*)(target + (size_t)cellw * FPC);
    #pragma unroll
    for (int it = 0; it < 8; ++it) {
      const int idx = it * 64 + lane;
      if (idx < TILE_F4) pr[it] = __builtin_nontemporal_load(gp + idx);
    }
    #pragma unroll
    for (int it = 0; it < 8; ++it) {
      const int idx = it * 64 + lane;
      if (idx < TILE_F4) tr[it] = __builtin_nontemporal_load(gt + idx);
    }
  }

  union Buf { float2 v[FPC / 2]; float f[FPC]; };
  Buf P, T;

  // ---- pred LDS round trip (wave-private region, no barrier needed) ----
  {
    vfloat4* l = (vfloat4*)myld;
    #pragma unroll
    for (int it = 0; it < 8; ++it) {
      const int idx = it * 64 + lane;
      if (idx < TILE_F4) l[idx] = pr[it];
    }
    const float2* l2 = (const float2*)(myld + lane * FPC);
    #pragma unroll
    for (int i = 0; i < FPC / 2; ++i) P.v[i] = l2[i];
  }
  // order target LDS writes after pred LDS reads (same region). Target GLOBAL
  // loads were issued above and cannot sink past a memory clobber.
  asm volatile("" ::: "memory");
  // ---- target LDS round trip ----
  {
    vfloat4* l = (vfloat4*)myld;
    #pragma unroll
    for (int it = 0; it < 8; ++it) {
      const int idx = it * 64 + lane;
      if (idx < TILE_F4) l[idx] = tr[it];
    }
    const float2* l2 = (const float2*)(myld + lane * FPC);
    #pragma unroll
    for (int i = 0; i < FPC / 2; ++i) T.v[i] = l2[i];
  }

  const float* p = P.f;
  const float* t = T.f;

  // ---- per-cell loss (identical arithmetic to R8) ----
  const float gx = (float)(cell % S);
  const float gy = (float)((cell / S) % S);
  const float mask = (t[9] > 0.0f) ? 1.0f : 0.0f;

  float iou[2];
  #pragma unroll
  for (int b = 0; b < 2; ++b) {
    const float* pb = p + 5 * b;
    const float* tb = t + 5 * b;
    // _convert_boxes: x0=(x+gx)*STEP - w/2, clip all 4 at 0
    float px = fmaxf((pb[0] + gx) * STEP - pb[2] * 0.5f, 0.0f);
    float py = fmaxf((pb[1] + gy) * STEP - pb[3] * 0.5f, 0.0f);
    float pw = fmaxf(pb[2], 0.0f);
    float ph = fmaxf(pb[3], 0.0f);
    float tx = fmaxf((tb[0] + gx) * STEP - tb[2] * 0.5f, 0.0f);
    float ty = fmaxf((tb[1] + gy) * STEP - tb[3] * 0.5f, 0.0f);
    float tw = fmaxf(tb[2], 0.0f);
    float th = fmaxf(tb[3], 0.0f);
    float iw = fmaxf(pw + tw - (fmaxf(px + pw, tx + tw) - fminf(px, tx)), 0.0f);
    float ih = fmaxf(ph + th - (fmaxf(py + ph, ty + th) - fminf(py, ty)), 0.0f);
    float inter = iw * ih;
    float uni = pw * ph + tw * th - inter;
    iou[b] = inter / (uni + EPS);
  }
  // jnp.argmax: first max wins → box 0 on tie
  const int best = (iou[1] > iou[0]) ? 1 : 0;

  float loss = 0.0f;
  #pragma unroll
  for (int b = 0; b < 2; ++b) {
    const float* pb = p + 5 * b;
    const float* tb = t + 5 * b;
    float obj = (b == best) ? mask : 0.0f;
    float d0 = pb[0] - tb[0];
    float d1 = pb[1] - tb[1];
    float d2 = pb[2] - tb[2];
    float d3 = pb[3] - tb[3];
    loss += 5.0f * obj * (d0 * d0 + d1 * d1 + d2 * d2 + d3 * d3);  // coord
    float dc = pb[4] - iou[b];
    loss += obj * dc * dc;                                         // conf
    loss += 0.5f * (1.0f - obj) * pb[4] * pb[4];                   // noobj
  }
  float cls = 0.0f;
  #pragma unroll
  for (int k = 10; k < 30; ++k) {
    float d = p[k] - t[k];
    cls += d * d;
  }
  loss += mask * cls;                                              // class

  // ---- block reduce: wave shuffle → LDS → one partial per block ----
  #pragma unroll
  for (int off = 32; off > 0; off >>= 1)
    loss += __shfl_down(loss, off, 64);
  if ((tid & 63) == 0) wsum[wid] = loss;
  __syncthreads();
  if (tid == 0) {
    float total = 0.0f;
    #pragma unroll
    for (int w = 0; w < WAVES; ++w) total += wsum[w];
    partial[blockIdx.x] = total;          // distinct address — no atomic
    __threadfence();                      // release partial before ticket
    ticket = atomicAdd(ticket_ctr, 1u);   // device-scope RMW
  }
  __syncthreads();

  // ---- last block performs the final reduce (bit-identical to old kernel) --
  if (ticket == (unsigned)(nblocks - 1)) {
    __threadfence();                      // acquire: other blocks' partials
    float s = 0.0f;
    for (int i = tid; i < nblocks; i += BLK)
      s += __hip_atomic_load(&partial[i], __ATOMIC_RELAXED,
                             __HIP_MEMORY_SCOPE_AGENT);
    #pragma unroll
    for (int off = 32; off > 0; off >>= 1)
      s += __shfl_down(s, off, 64);
    if ((tid & 63) == 0) wsum[tid >> 6] = s;
    __syncthreads();
    if (tid == 0)
      out[0] = (wsum[0] + wsum[1] + wsum[2] + wsum[3]) * invN;
  }
}

extern "C" void kernel_launch(void* const* d_in, const int* in_sizes, int n_in,
                              void* d_out, int out_size, void* d_ws, size_t ws_size,
                              hipStream_t stream) {
  const float* pred = (const float*)d_in[0];
  const float* target = (const float*)d_in[1];
  float* out = (float*)d_out;
  float* partial = (float*)d_ws;             // 3136 floats = 12544 B
  unsigned int* ticket_ctr = (unsigned int*)((char*)d_ws + 12544);

  const int ncells = in_sizes[0] / FPC;      // 802816
  const int nblocks = ncells / BLK;          // 3136 (exact)
  const float invN = 1.0f / (float)(ncells / (S * S));  // 1/16384

  hipMemsetAsync(ticket_ctr, 0, sizeof(unsigned int), stream);
  yolo_fused_kernel<<<nblocks, BLK, 0, stream>>>(pred, target, partial,
                                                 ticket_ctr, out,
                                                 nblocks, invN);
}

// Round 5
// 188.580 us; speedup vs baseline: 1.8113x; 1.8113x over previous
//
#include <hip/hip_runtime.h>

// YOLO-v1 loss, fp32, N=16384, S=7, B=2, C=20 → 30 floats/cell, 802816 cells.
// R13 = R12 minus the fused reduce (bisect).
// R12 post-mortem: kernel 72→190us with IDENTICAL memory counters (FETCH
// 94.1MB, VALUBusy 3%) → regression not in the load path. Culprit theory: the
// last-block reduce added __threadfence() (agent-scope release) + one
// device-scope atomicAdd per block. MI355X per-XCD L2s are non-coherent, so
// an agent release must write back dirty L2 lines; 3136 blocks × (L2
// writeback + contended RMW on one address) ≈ ~120us, traffic-independent —
// matching the flat 190.4±0.3us across replays @ only 505 GB/s.
// R13 keeps: NT dense dwordx4 for BOTH inputs (R8-proven: round-0 top-5 were
// all >=56.0us harness fills, yolo absent => R8 kernel <56.5us, beats the
// 2.7 TB/s pin R11 fell back onto), single-latency-window register staging,
// wave-private LDS round trips. Restores: separate 1-block reduce kernel,
// bit-identical summation order (absmax must stay 0.0).
// Predict: partial kernel 40-56us (if register staging was innocent), FETCH
// ~94MB, total ~170-190us. If kernel stays ~190us → staging is the culprit,
// revert to exact R8 next.

typedef float vfloat4 __attribute__((ext_vector_type(4)));

constexpr int S = 7;
constexpr int FPC = 30;           // floats per cell
constexpr int BLK = 256;          // 4 waves
constexpr int WAVES = BLK / 64;
constexpr int TILE_F4 = 64 * FPC / 4;   // 480 float4 per wave tile
constexpr float STEP = 1.0f / 7.0f;
constexpr float EPS = 1e-10f;

__global__ __launch_bounds__(BLK) void yolo_partial_kernel(
    const float* __restrict__ pred,
    const float* __restrict__ target,
    float* __restrict__ partial) {
  __shared__ float lds[WAVES][64 * FPC];   // 7680 B per wave region
  __shared__ float wsum[WAVES];

  const int tid = threadIdx.x;
  const int lane = tid & 63;
  const int wid = tid >> 6;
  const int cellw = blockIdx.x * BLK + wid * 64;  // wave's first cell
  const int cell = cellw + lane;

  float* myld = lds[wid];

  // ---- single latency window: both inputs, dense wave-contiguous NT 16B ----
  vfloat4 pr[8], tr[8];
  {
    const vfloat4* gp = (const vfloat4*)(pred + (size_t)cellw * FPC);
    const vfloat4* gt = (const vfloat4*)(target + (size_t)cellw * FPC);
    #pragma unroll
    for (int it = 0; it < 8; ++it) {
      const int idx = it * 64 + lane;
      if (idx < TILE_F4) pr[it] = __builtin_nontemporal_load(gp + idx);
    }
    #pragma unroll
    for (int it = 0; it < 8; ++it) {
      const int idx = it * 64 + lane;
      if (idx < TILE_F4) tr[it] = __builtin_nontemporal_load(gt + idx);
    }
  }

  union Buf { float2 v[FPC / 2]; float f[FPC]; };
  Buf P, T;

  // ---- pred LDS round trip (wave-private region, no barrier needed) ----
  {
    vfloat4* l = (vfloat4*)myld;
    #pragma unroll
    for (int it = 0; it < 8; ++it) {
      const int idx = it * 64 + lane;
      if (idx < TILE_F4) l[idx] = pr[it];
    }
    const float2* l2 = (const float2*)(myld + lane * FPC);
    #pragma unroll
    for (int i = 0; i < FPC / 2; ++i) P.v[i] = l2[i];
  }
  // order target LDS writes after pred LDS reads (same region). Target GLOBAL
  // loads were issued above and cannot sink past a memory clobber.
  asm volatile("" ::: "memory");
  // ---- target LDS round trip ----
  {
    vfloat4* l = (vfloat4*)myld;
    #pragma unroll
    for (int it = 0; it < 8; ++it) {
      const int idx = it * 64 + lane;
      if (idx < TILE_F4) l[idx] = tr[it];
    }
    const float2* l2 = (const float2*)(myld + lane * FPC);
    #pragma unroll
    for (int i = 0; i < FPC / 2; ++i) T.v[i] = l2[i];
  }

  const float* p = P.f;
  const float* t = T.f;

  // ---- per-cell loss (identical arithmetic to R8) ----
  const float gx = (float)(cell % S);
  const float gy = (float)((cell / S) % S);
  const float mask = (t[9] > 0.0f) ? 1.0f : 0.0f;

  float iou[2];
  #pragma unroll
  for (int b = 0; b < 2; ++b) {
    const float* pb = p + 5 * b;
    const float* tb = t + 5 * b;
    // _convert_boxes: x0=(x+gx)*STEP - w/2, clip all 4 at 0
    float px = fmaxf((pb[0] + gx) * STEP - pb[2] * 0.5f, 0.0f);
    float py = fmaxf((pb[1] + gy) * STEP - pb[3] * 0.5f, 0.0f);
    float pw = fmaxf(pb[2], 0.0f);
    float ph = fmaxf(pb[3], 0.0f);
    float tx = fmaxf((tb[0] + gx) * STEP - tb[2] * 0.5f, 0.0f);
    float ty = fmaxf((tb[1] + gy) * STEP - tb[3] * 0.5f, 0.0f);
    float tw = fmaxf(tb[2], 0.0f);
    float th = fmaxf(tb[3], 0.0f);
    float iw = fmaxf(pw + tw - (fmaxf(px + pw, tx + tw) - fminf(px, tx)), 0.0f);
    float ih = fmaxf(ph + th - (fmaxf(py + ph, ty + th) - fminf(py, ty)), 0.0f);
    float inter = iw * ih;
    float uni = pw * ph + tw * th - inter;
    iou[b] = inter / (uni + EPS);
  }
  // jnp.argmax: first max wins → box 0 on tie
  const int best = (iou[1] > iou[0]) ? 1 : 0;

  float loss = 0.0f;
  #pragma unroll
  for (int b = 0; b < 2; ++b) {
    const float* pb = p + 5 * b;
    const float* tb = t + 5 * b;
    float obj = (b == best) ? mask : 0.0f;
    float d0 = pb[0] - tb[0];
    float d1 = pb[1] - tb[1];
    float d2 = pb[2] - tb[2];
    float d3 = pb[3] - tb[3];
    loss += 5.0f * obj * (d0 * d0 + d1 * d1 + d2 * d2 + d3 * d3);  // coord
    float dc = pb[4] - iou[b];
    loss += obj * dc * dc;                                         // conf
    loss += 0.5f * (1.0f - obj) * pb[4] * pb[4];                   // noobj
  }
  float cls = 0.0f;
  #pragma unroll
  for (int k = 10; k < 30; ++k) {
    float d = p[k] - t[k];
    cls += d * d;
  }
  loss += mask * cls;                                              // class

  // ---- reduce: wave shuffle → LDS → one plain store per block ----
  #pragma unroll
  for (int off = 32; off > 0; off >>= 1)
    loss += __shfl_down(loss, off, 64);
  if ((tid & 63) == 0) wsum[wid] = loss;
  __syncthreads();
  if (tid == 0) {
    float total = 0.0f;
    #pragma unroll
    for (int w = 0; w < WAVES; ++w) total += wsum[w];
    partial[blockIdx.x] = total;          // distinct address — no atomic
  }
}

__global__ __launch_bounds__(256) void yolo_reduce_kernel(
    const float* __restrict__ partial, float* __restrict__ out,
    int n, float invN) {
  __shared__ float wsum[4];
  const int tid = threadIdx.x;
  float s = 0.0f;
  for (int i = tid; i < n; i += 256) s += partial[i];
  #pragma unroll
  for (int off = 32; off > 0; off >>= 1)
    s += __shfl_down(s, off, 64);
  if ((tid & 63) == 0) wsum[tid >> 6] = s;
  __syncthreads();
  if (tid == 0)
    out[0] = (wsum[0] + wsum[1] + wsum[2] + wsum[3]) * invN;
}

extern "C" void kernel_launch(void* const* d_in, const int* in_sizes, int n_in,
                              void* d_out, int out_size, void* d_ws, size_t ws_size,
                              hipStream_t stream) {
  const float* pred = (const float*)d_in[0];
  const float* target = (const float*)d_in[1];
  float* out = (float*)d_out;
  float* partial = (float*)d_ws;             // 3136 floats = 12.5 KB

  const int ncells = in_sizes[0] / FPC;      // 802816
  const int nblocks = ncells / BLK;          // 3136 (exact)
  const float invN = 1.0f / (float)(ncells / (S * S));  // 1/16384

  yolo_partial_kernel<<<nblocks, BLK, 0, stream>>>(pred, target, partial);
  yolo_reduce_kernel<<<1, 256, 0, stream>>>(partial, out, nblocks, invN);
}